// Round 1
// baseline (4263.501 us; speedup 1.0000x reference)
//
#include <hip/hip_runtime.h>

// ---------------- problem constants ----------------
#define Hd   256
#define Bd   16
#define Td   128
#define Ld   50
#define Vd   32000
#define G5H  1280     // 5*H
#define NWG  16

typedef __attribute__((ext_vector_type(8))) short short8v;  // 8 bf16 (4 VGPRs)
typedef __attribute__((ext_vector_type(4))) float f32x4;

__device__ __forceinline__ unsigned short f2bu(float f) {   // f32 -> bf16 bits (RNE)
  unsigned u = __float_as_uint(f);
  unsigned r = (u + 0x7fffu + ((u >> 16) & 1u)) >> 16;
  return (unsigned short)r;
}
__device__ __forceinline__ float bu2f(unsigned short b) {
  return __uint_as_float(((unsigned)b) << 16);
}
__device__ __forceinline__ void st_dev(float* p, float v) {
  __hip_atomic_store(p, v, __ATOMIC_RELAXED, __HIP_MEMORY_SCOPE_AGENT);
}
__device__ __forceinline__ float ld_dev(const float* p) {
  return __hip_atomic_load((float*)p, __ATOMIC_RELAXED, __HIP_MEMORY_SCOPE_AGENT);
}
__device__ __forceinline__ float sigm(float x) { return 1.f / (1.f + __expf(-x)); }

__device__ __forceinline__ void grid_barrier(unsigned* bar) {
  __syncthreads();
  if (threadIdx.x == 0) {
    __threadfence();  // release our stores (L2 writeback for cross-XCD)
    unsigned* cnt = bar;
    unsigned* gen = bar + 16;
    unsigned g = __hip_atomic_load(gen, __ATOMIC_RELAXED, __HIP_MEMORY_SCOPE_AGENT);
    unsigned arr = __hip_atomic_fetch_add(cnt, 1u, __ATOMIC_ACQ_REL, __HIP_MEMORY_SCOPE_AGENT);
    if (arr == NWG - 1) {
      __hip_atomic_store(cnt, 0u, __ATOMIC_RELAXED, __HIP_MEMORY_SCOPE_AGENT);
      __hip_atomic_store(gen, g + 1u, __ATOMIC_RELEASE, __HIP_MEMORY_SCOPE_AGENT);
    } else {
      int guard = 0;
      while (__hip_atomic_load(gen, __ATOMIC_ACQUIRE, __HIP_MEMORY_SCOPE_AGENT) == g) {
        __builtin_amdgcn_s_sleep(2);
        if (++guard > (1 << 22)) break;  // safety: never hang the harness
      }
    }
    __threadfence();  // acquire side: invalidate stale lines
  }
  __syncthreads();
}

// ---------------- fp32 -> bf16 weight conversion ----------------
__global__ __launch_bounds__(256) void conv_kernel(
    const float* __restrict__ wv, const float* __restrict__ w_ih,
    const float* __restrict__ fcW,
    unsigned short* __restrict__ wv_b, unsigned short* __restrict__ wih_b,
    unsigned short* __restrict__ fcw_b)
{
  const long NWV = 2048000, NWI = 81920, NFC = 2048000;  // float4 groups
  const long total = NWV + NWI + NFC;
  for (long idx = (long)blockIdx.x * blockDim.x + threadIdx.x; idx < total;
       idx += (long)gridDim.x * blockDim.x) {
    const float* src; unsigned short* dst; long off;
    if (idx < NWV)            { src = wv;   dst = wv_b;  off = idx; }
    else if (idx < NWV + NWI) { src = w_ih; dst = wih_b; off = idx - NWV; }
    else                      { src = fcW;  dst = fcw_b; off = idx - NWV - NWI; }
    float4 v = *(const float4*)(src + off * 4);
    ushort4 o;
    o.x = f2bu(v.x); o.y = f2bu(v.y); o.z = f2bu(v.z); o.w = f2bu(v.w);
    *(ushort4*)(dst + off * 4) = o;
  }
}

// ---------------- per-batch prep: goal embed, ht0, goal_term, E, sumE ----------------
__global__ __launch_bounds__(256) void prep_kernel(
    const int* __restrict__ g, const int* __restrict__ ingr,
    const float* __restrict__ wv, const float* __restrict__ Ug,
    const float* __restrict__ Ym, const float* __restrict__ yb,
    float* __restrict__ E_ws, float* __restrict__ sumE,
    float* __restrict__ goal_ws, float* HT2, float* TMP)
{
  __shared__ float ge[256];
  const int b = blockIdx.x, tid = threadIdx.x;
  float s = 0.f;
  for (int i = 0; i < 8; ++i) s += wv[((size_t)g[(b << 3) + i] << 8) + tid];
  ge[tid] = s;
  __syncthreads();
  float h0 = 0.f, gt = 0.f;
  const float* ur = Ug + (tid << 8);
  const float* yr = Ym + (tid << 8);
#pragma unroll 8
  for (int k = 0; k < Hd; k += 4) {
    float4 gv = *(const float4*)(ge + k);
    float4 uv = *(const float4*)(ur + k);
    float4 yv = *(const float4*)(yr + k);
    h0 = fmaf(gv.x, uv.x, h0); h0 = fmaf(gv.y, uv.y, h0);
    h0 = fmaf(gv.z, uv.z, h0); h0 = fmaf(gv.w, uv.w, h0);
    gt = fmaf(gv.x, yv.x, gt); gt = fmaf(gv.y, yv.y, gt);
    gt = fmaf(gv.z, yv.z, gt); gt = fmaf(gv.w, yv.w, gt);
  }
  st_dev(HT2 + (tid << 4) + b, h0);          // HT2 layout [c][b]
  goal_ws[(tid << 4) + b] = gt + yb[tid];    // goal_term layout [c][b]
  float se = 0.f;
  for (int l = 0; l < Ld; ++l) {
    float v = wv[((size_t)ingr[b * Ld + l] << 8) + tid];
    E_ws[((size_t)(b * Ld + l) << 8) + tid] = v;
    se += v;
  }
  sumE[(b << 8) + tid] = se;                 // [b][k]
  st_dev(TMP + (b << 8) + tid, se);          // tmp(0) = sumE
}

// ---------------- bf16 MFMA GEMM (128x128 tile, K=256), two epilogues ----------------
// MODE 0: gi = gather(wv,recipe) @ w_ih^T + b_ih  ->  gi_ws[t][n][b]
// MODE 1: logits = out_all @ fcW^T + fcb          ->  d_out[row][v]
template <int MODE>
__global__ __launch_bounds__(256) void gemm_bf16(
    const unsigned short* __restrict__ A, const unsigned short* __restrict__ Bmat,
    const int* __restrict__ ridx, const float* __restrict__ bias,
    float* __restrict__ C)
{
  __shared__ unsigned short As[128 * 64];
  __shared__ unsigned short Bs[128 * 64];
  const int tid = threadIdx.x;
  const int m0 = blockIdx.x << 7, n0 = blockIdx.y << 7;
  const int wave = tid >> 6, lane = tid & 63;
  const int wm = wave >> 1, wn = wave & 1;
  const int lr = lane & 15, lg = lane >> 4;

  f32x4 acc[4][4];
#pragma unroll
  for (int i = 0; i < 4; ++i)
#pragma unroll
    for (int jj = 0; jj < 4; ++jj) acc[i][jj] = (f32x4){0.f, 0.f, 0.f, 0.f};

  const int srow = tid >> 1, shalf = tid & 1;
  const unsigned short* arow;
  {
    int gm = m0 + srow;
    if (MODE == 0) {
      int tt = gm >> 4, bb = gm & 15;
      arow = A + (size_t)ridx[bb * Td + tt] * Hd;
    } else {
      arow = A + (size_t)gm * Hd;
    }
  }
  const unsigned short* brow = Bmat + (size_t)(n0 + srow) * Hd;

  for (int k0 = 0; k0 < Hd; k0 += 64) {
#pragma unroll
    for (int c = 0; c < 4; ++c) {
      int k = shalf * 32 + c * 8;
      uint4 va = *(const uint4*)(arow + k0 + k);
      uint4 vb = *(const uint4*)(brow + k0 + k);
      int byo = (srow << 7) + ((k << 1) ^ ((srow & 7) << 4));  // XOR swizzle
      *(uint4*)((char*)As + byo) = va;
      *(uint4*)((char*)Bs + byo) = vb;
    }
    __syncthreads();
#pragma unroll
    for (int kk = 0; kk < 2; ++kk) {
      short8v af[4], bfr[4];
      const int kb = kk * 32 + lg * 8;
#pragma unroll
      for (int i = 0; i < 4; ++i) {
        int ar = wm * 64 + i * 16 + lr;
        af[i] = *(const short8v*)((const char*)As + (ar << 7) + ((kb << 1) ^ ((ar & 7) << 4)));
        int br = wn * 64 + i * 16 + lr;
        bfr[i] = *(const short8v*)((const char*)Bs + (br << 7) + ((kb << 1) ^ ((br & 7) << 4)));
      }
#pragma unroll
      for (int i = 0; i < 4; ++i)
#pragma unroll
        for (int jj = 0; jj < 4; ++jj)
          acc[i][jj] = __builtin_amdgcn_mfma_f32_16x16x32_bf16(af[i], bfr[jj], acc[i][jj], 0, 0, 0);
    }
    __syncthreads();
  }
#pragma unroll
  for (int i = 0; i < 4; ++i)
#pragma unroll
    for (int jj = 0; jj < 4; ++jj) {
      int col = n0 + wn * 64 + jj * 16 + lr;
      float bv = bias[col];
#pragma unroll
      for (int r = 0; r < 4; ++r) {
        int row = m0 + wm * 64 + i * 16 + lg * 4 + r;
        float v = acc[i][jj][r] + bv;
        if (MODE == 0) {
          int tt = row >> 4, bb = row & 15;
          C[((size_t)tt * G5H + col) * Bd + bb] = v;
        } else {
          C[(size_t)row * Vd + col] = v;
        }
      }
    }
}

// ---------------- persistent recurrence kernel: 16 WGs, 3 barriers/step ----------------
// WG j owns: h-columns [16j,16j+16) of all 5 gates (w_hh slice fp32 in LDS) AND batch j
// for the attention phase (E[j] bf16 in LDS).
#define RNN_SMEM 149056
__global__ __launch_bounds__(640, 1) void rnn_kernel(
    const float* __restrict__ w_hh, const float* __restrict__ b_hh,
    const float* __restrict__ Zm, const float* __restrict__ Pm,
    const float* __restrict__ Sm, const float* __restrict__ z_bias,
    const float* __restrict__ gi, const float* __restrict__ goal_ws,
    const float* __restrict__ E_ws, const float* __restrict__ sumE,
    float* HT2, float* TMP, float* HPROJ,
    unsigned short* __restrict__ out_all, float* __restrict__ d_out,
    unsigned* bar)
{
  extern __shared__ char smem[];
  float* w_lds   = (float*)smem;             // 80*256  (XOR-swizzled rows)
  float* ht_lds  = w_lds + 20480;            // 16*260
  float* tmp_lds = ht_lds + 4160;            // 16*260
  float* gh_lds  = tmp_lds + 4160;           // 16*84
  float* hp_lds  = gh_lds + 1344;            // 256
  float* a_lds   = hp_lds + 256;             // 64
  float* d_lds   = a_lds + 64;               // 64
  float* an_lds  = d_lds + 64;               // 64
  float* au_lds  = an_lds + 64;              // 64
  float* sd_lds  = au_lds + 64;              // 4
  float* ref_lds = sd_lds + 4;               // 4
  unsigned short* E_lds = (unsigned short*)(ref_lds + 4);  // 50*264 bf16

  const int j = blockIdx.x;
  const int tid = threadIdx.x;
  const int hc0 = j << 4;

  // one-time staging
  for (int idx = tid; idx < 80 * 256; idx += 640) {
    int r = idx >> 8, k = idx & 255;
    int grow = ((r >> 4) << 8) + hc0 + (r & 15);   // gate*256 + h-col
    w_lds[(r << 8) + (k ^ ((r & 7) << 2))] = w_hh[((size_t)grow << 8) + k];
  }
  for (int idx = tid; idx < 4096; idx += 640) {    // ht0
    int b = idx & 15, c = idx >> 4;
    ht_lds[b * 260 + c] = ld_dev(HT2 + idx);
  }
  for (int idx = tid; idx < Ld * Hd; idx += 640) {
    int l = idx >> 8, k = idx & 255;
    E_lds[l * 264 + k] = f2bu(E_ws[((size_t)(j * Ld + l) << 8) + k]);
  }
  if (tid < 64) a_lds[tid] = 0.f;
  __syncthreads();

  for (int t = 0; t < Td; ++t) {
    // ---------- phase 1: gh slice + gates + ht2 slice ----------
    for (int idx = tid; idx < 4096; idx += 640) {  // stage tmp (published prev step)
      int b = idx >> 8, k = idx & 255;
      tmp_lds[b * 260 + k] = ld_dev(TMP + idx);
    }
    __syncthreads();
    {
      int b = tid & 15, rq = tid >> 4;             // rq in [0,40)
      int r0 = rq << 1, r1 = r0 + 1;
      int g0 = r0 >> 4, g1 = r1 >> 4;
      int grow0 = (g0 << 8) + hc0 + (r0 & 15);
      int grow1 = (g1 << 8) + hc0 + (r1 & 15);
      // gate n (g==2) keeps i-part separate (r_t multiplies only h_n)
      float acc0 = b_hh[grow0] + (g0 == 2 ? 0.f : gi[((size_t)(t * G5H + grow0) << 4) + b]);
      float acc1 = b_hh[grow1] + (g1 == 2 ? 0.f : gi[((size_t)(t * G5H + grow1) << 4) + b]);
      const float* htp = ht_lds + b * 260;
      const float* w0 = w_lds + (r0 << 8);
      const float* w1 = w_lds + (r1 << 8);
      const int sw0 = (r0 & 7) << 2, sw1 = (r1 & 7) << 2;
#pragma unroll 8
      for (int k = 0; k < Hd; k += 4) {
        float4 h  = *(const float4*)(htp + k);
        float4 wa = *(const float4*)(w0 + (k ^ sw0));
        float4 wb = *(const float4*)(w1 + (k ^ sw1));
        acc0 = fmaf(h.x, wa.x, acc0); acc0 = fmaf(h.y, wa.y, acc0);
        acc0 = fmaf(h.z, wa.z, acc0); acc0 = fmaf(h.w, wa.w, acc0);
        acc1 = fmaf(h.x, wb.x, acc1); acc1 = fmaf(h.y, wb.y, acc1);
        acc1 = fmaf(h.z, wb.z, acc1); acc1 = fmaf(h.w, wb.w, acc1);
      }
      gh_lds[b * 84 + r0] = acc0;
      gh_lds[b * 84 + r1] = acc1;
    }
    __syncthreads();
    if (tid < 256) {
      int b = tid & 15, cl = tid >> 4;
      int c = hc0 + cl;
      const float* zr = Zm + ((size_t)c << 8);     // Z slice stays L1-hot (16 KB)
      const float* tp = tmp_lds + b * 260;
      float zd = 0.f;
#pragma unroll 8
      for (int k = 0; k < Hd; k += 4) {
        float4 zv = *(const float4*)(zr + k);
        float4 tv = *(const float4*)(tp + k);
        zd = fmaf(zv.x, tv.x, zd); zd = fmaf(zv.y, tv.y, zd);
        zd = fmaf(zv.z, tv.z, zd); zd = fmaf(zv.w, tv.w, zd);
      }
      float pre_r = gh_lds[b * 84 + cl];
      float pre_u = gh_lds[b * 84 + 16 + cl];
      float hn    = gh_lds[b * 84 + 32 + cl];
      float pre_g = gh_lds[b * 84 + 48 + cl];
      float pre_i = gh_lds[b * 84 + 64 + cl];
      float i_n = gi[((size_t)(t * G5H + 512 + c) << 4) + b];
      float zt = sigm(pre_u), rt = sigm(pre_r), st = sigm(pre_g), qt = sigm(pre_i);
      float htl = tanhf(i_n + rt * hn + st * goal_ws[(c << 4) + b] + qt * (zd + z_bias[c]));
      float prev = ht_lds[b * 260 + c];
      float h2 = htl + zt * (prev - htl);
      st_dev(HT2 + (c << 4) + b, h2);
    }
    grid_barrier(bar);
    // ---------- phase 2: h_proj slice ----------
    for (int idx = tid; idx < 4096; idx += 640) {  // stage full current ht2
      int b = idx & 15, c = idx >> 4;
      ht_lds[b * 260 + c] = ld_dev(HT2 + idx);
    }
    __syncthreads();
    if (tid < 256) {
      int b = tid & 15, cl = tid >> 4;
      int c = hc0 + cl;
      const float* pr = Pm + ((size_t)c << 8);     // P slice L1-hot
      const float* hh = ht_lds + b * 260;
      float hp = 0.f;
#pragma unroll 8
      for (int k = 0; k < Hd; k += 4) {
        float4 pv = *(const float4*)(pr + k);
        float4 hv = *(const float4*)(hh + k);
        hp = fmaf(pv.x, hv.x, hp); hp = fmaf(pv.y, hv.y, hp);
        hp = fmaf(pv.z, hv.z, hp); hp = fmaf(pv.w, hv.w, hp);
      }
      st_dev(HPROJ + (c << 4) + b, hp);
    }
    grid_barrier(bar);
    // ---------- phase 3: attention for batch j ----------
    if (tid < 192) {                               // S dots (ref pre-softmax)
      int w = tid >> 6, ln = tid & 63;
      float4 sv = *(const float4*)(Sm + (w << 8) + (ln << 2));
      float4 hv = *(const float4*)(ht_lds + j * 260 + (ln << 2));
      float p = sv.x * hv.x + sv.y * hv.y + sv.z * hv.z + sv.w * hv.w;
      p += __shfl_xor(p, 1);  p += __shfl_xor(p, 2);  p += __shfl_xor(p, 4);
      p += __shfl_xor(p, 8);  p += __shfl_xor(p, 16); p += __shfl_xor(p, 32);
      if (ln == 0) sd_lds[w] = p;
    } else if (tid >= 256 && tid < 512) {          // stage h_proj[j]
      int c = tid - 256;
      hp_lds[c] = ld_dev(HPROJ + (c << 4) + j);
    }
    __syncthreads();
    if (tid < 200) {                               // d_l = h_proj . E_l
      int l = tid >> 2, q = tid & 3;
      const unsigned short* er = E_lds + l * 264 + (q << 6);
      const float* hq = hp_lds + (q << 6);
      float p = 0.f;
#pragma unroll 8
      for (int i = 0; i < 32; ++i) {
        unsigned u = *(const unsigned*)(er + 2 * i);
        float e0 = __uint_as_float(u << 16);
        float e1 = __uint_as_float(u & 0xffff0000u);
        p = fmaf(e0, hq[2 * i], p);
        p = fmaf(e1, hq[2 * i + 1], p);
      }
      p += __shfl_xor(p, 1); p += __shfl_xor(p, 2);
      if (q == 0) d_lds[l] = p;
    } else if (tid == 600) {                       // ref = softmax(BETA*sd)
      float s0 = 5.0f * sd_lds[0], s1 = 5.0f * sd_lds[1], s2 = 5.0f * sd_lds[2];
      float m = fmaxf(s0, fmaxf(s1, s2));
      float e0 = __expf(s0 - m), e1 = __expf(s1 - m), e2 = __expf(s2 - m);
      float inv = 1.f / (e0 + e1 + e2);
      ref_lds[0] = e0 * inv; ref_lds[1] = e1 * inv; ref_lds[2] = e2 * inv;
    }
    __syncthreads();
    if (tid < 128) {                               // alpha_n (wave0) / alpha_u (wave1)
      int which = tid >> 6;
      int l = tid & 63;
      float dv;
      if (which == 0) dv = (l < Ld) ? 2.0f * (1.f - a_lds[l]) * d_lds[l] : -3.4e38f;
      else            dv = (l < Ld) ? 2.0f * a_lds[l] * d_lds[l]         : -3.4e38f;
      float m = dv;
      m = fmaxf(m, __shfl_xor(m, 1));  m = fmaxf(m, __shfl_xor(m, 2));
      m = fmaxf(m, __shfl_xor(m, 4));  m = fmaxf(m, __shfl_xor(m, 8));
      m = fmaxf(m, __shfl_xor(m, 16)); m = fmaxf(m, __shfl_xor(m, 32));
      float e = (l < Ld) ? __expf(dv - m) : 0.f;
      float ss = e;
      ss += __shfl_xor(ss, 1);  ss += __shfl_xor(ss, 2);  ss += __shfl_xor(ss, 4);
      ss += __shfl_xor(ss, 8);  ss += __shfl_xor(ss, 16); ss += __shfl_xor(ss, 32);
      float al = e / ss;
      if (which == 0) an_lds[l] = al; else au_lds[l] = al;
    }
    __syncthreads();
    if (tid < 256) {                               // c_n, c_u, tmp_next, out
      int k = tid;
      float accn = 0.f, accu = 0.f, acct = 0.f;
#pragma unroll 10
      for (int l = 0; l < Ld; ++l) {
        float e = bu2f(E_lds[l * 264 + k]);
        accn = fmaf(an_lds[l], e, accn);
        accu = fmaf(au_lds[l], e, accu);
        acct = fmaf(a_lds[l], e, acct);            // a BEFORE this step's update
      }
      float outv = ref_lds[0] * hp_lds[k] + ref_lds[1] * accn + ref_lds[2] * accu;
      out_all[(((j << 7) + t) << 8) + k] = f2bu(outv);
      st_dev(TMP + (j << 8) + k, sumE[(j << 8) + k] - acct);  // tmp(t+1)
      if (t == Td - 1) {
        d_out[(size_t)65536000 + (j << 8) + k] = ht_lds[j * 260 + k];  // ht out
        for (int l = 0; l < Ld; ++l) {             // E_new = (1-a_pre)*E (fp32 source)
          size_t o = ((size_t)(j * Ld + l) << 8) + k;
          d_out[(size_t)65540896 + o] = (1.f - a_lds[l]) * E_ws[o];
        }
      }
    }
    __syncthreads();
    if (tid < Ld) {                                // a update (after E_new/c use)
      float na = a_lds[tid] + ref_lds[1] * an_lds[tid];
      a_lds[tid] = na;
      if (t == Td - 1) d_out[(size_t)65540096 + j * Ld + tid] = na;
    }
    grid_barrier(bar);
  }
}

// ---------------- host launcher ----------------
extern "C" void kernel_launch(void* const* d_in, const int* in_sizes, int n_in,
                              void* d_out, int out_size, void* d_ws, size_t ws_size,
                              hipStream_t stream)
{
  const int*   recipe = (const int*)d_in[0];
  const int*   g      = (const int*)d_in[1];
  const int*   ingr   = (const int*)d_in[2];
  const float* wv     = (const float*)d_in[3];
  const float* w_ih   = (const float*)d_in[4];
  const float* w_hh   = (const float*)d_in[5];
  const float* b_ih   = (const float*)d_in[6];
  const float* b_hh   = (const float*)d_in[7];
  const float* Z      = (const float*)d_in[8];
  const float* Y      = (const float*)d_in[9];
  const float* Ug     = (const float*)d_in[10];
  const float* z_bias = (const float*)d_in[11];
  const float* y_bias = (const float*)d_in[12];
  const float* S      = (const float*)d_in[13];
  const float* P      = (const float*)d_in[14];
  const float* fcW    = (const float*)d_in[15];
  const float* fcb    = (const float*)d_in[16];
  float* out = (float*)d_out;
  char* ws = (char*)d_ws;

  size_t off = 0;
  unsigned* bar            = (unsigned*)(ws + off);        off += 256;
  unsigned short* wv_b     = (unsigned short*)(ws + off);  off += 16384000;
  unsigned short* wih_b    = (unsigned short*)(ws + off);  off += 655360;
  unsigned short* fcw_b    = (unsigned short*)(ws + off);  off += 16384000;
  float* gi_ws             = (float*)(ws + off);           off += 10485760;
  float* E_ws              = (float*)(ws + off);           off += 819200;
  float* sumE              = (float*)(ws + off);           off += 16384;
  float* goal_ws           = (float*)(ws + off);           off += 16384;
  float* HT2               = (float*)(ws + off);           off += 16384;
  float* TMP               = (float*)(ws + off);           off += 16384;
  float* HPROJ             = (float*)(ws + off);           off += 16384;
  unsigned short* out_all  = (unsigned short*)(ws + off);  off += 1048576;

  hipMemsetAsync(bar, 0, 256, stream);
  conv_kernel<<<2048, 256, 0, stream>>>(wv, w_ih, fcW, wv_b, wih_b, fcw_b);
  prep_kernel<<<16, 256, 0, stream>>>(g, ingr, wv, Ug, Y, y_bias,
                                      E_ws, sumE, goal_ws, HT2, TMP);
  gemm_bf16<0><<<dim3(16, 10), 256, 0, stream>>>(wv_b, wih_b, recipe, b_ih, gi_ws);
  hipFuncSetAttribute((const void*)rnn_kernel,
                      hipFuncAttributeMaxDynamicSharedMemorySize, RNN_SMEM);
  rnn_kernel<<<16, 640, RNN_SMEM, stream>>>(w_hh, b_hh, Z, P, S, z_bias,
                                            gi_ws, goal_ws, E_ws, sumE,
                                            HT2, TMP, HPROJ, out_all, out, bar);
  gemm_bf16<1><<<dim3(16, 250), 256, 0, stream>>>(out_all, fcw_b, nullptr, fcb, out);
}

// Round 2
// 3510.810 us; speedup vs baseline: 1.2144x; 1.2144x over previous
//
#include <hip/hip_runtime.h>

// ---------------- problem constants ----------------
#define Hd   256
#define Bd   16
#define Td   128
#define Ld   50
#define Vd   32000
#define G5H  1280     // 5*H
#define NWG  16

typedef __attribute__((ext_vector_type(8))) short short8v;  // 8 bf16 (4 VGPRs)
typedef __attribute__((ext_vector_type(4))) float f32x4;

__device__ __forceinline__ unsigned short f2bu(float f) {   // f32 -> bf16 bits (RNE)
  unsigned u = __float_as_uint(f);
  unsigned r = (u + 0x7fffu + ((u >> 16) & 1u)) >> 16;
  return (unsigned short)r;
}
__device__ __forceinline__ float bu2f(unsigned short b) {
  return __uint_as_float(((unsigned)b) << 16);
}
__device__ __forceinline__ void st_dev(float* p, float v) {
  __hip_atomic_store(p, v, __ATOMIC_RELAXED, __HIP_MEMORY_SCOPE_AGENT);
}
__device__ __forceinline__ float ld_dev(const float* p) {
  return __hip_atomic_load((float*)p, __ATOMIC_RELAXED, __HIP_MEMORY_SCOPE_AGENT);
}
__device__ __forceinline__ float sigm(float x) { return 1.f / (1.f + __expf(-x)); }

// ---------------- fp32 -> bf16 weight conversion ----------------
__global__ __launch_bounds__(256) void conv_kernel(
    const float* __restrict__ wv, const float* __restrict__ w_ih,
    const float* __restrict__ fcW,
    unsigned short* __restrict__ wv_b, unsigned short* __restrict__ wih_b,
    unsigned short* __restrict__ fcw_b)
{
  const long NWV = 2048000, NWI = 81920, NFC = 2048000;  // float4 groups
  const long total = NWV + NWI + NFC;
  for (long idx = (long)blockIdx.x * blockDim.x + threadIdx.x; idx < total;
       idx += (long)gridDim.x * blockDim.x) {
    const float* src; unsigned short* dst; long off;
    if (idx < NWV)            { src = wv;   dst = wv_b;  off = idx; }
    else if (idx < NWV + NWI) { src = w_ih; dst = wih_b; off = idx - NWV; }
    else                      { src = fcW;  dst = fcw_b; off = idx - NWV - NWI; }
    float4 v = *(const float4*)(src + off * 4);
    ushort4 o;
    o.x = f2bu(v.x); o.y = f2bu(v.y); o.z = f2bu(v.z); o.w = f2bu(v.w);
    *(ushort4*)(dst + off * 4) = o;
  }
}

// ---------------- per-batch prep: goal embed, ht0, goal_term, E, sumE ----------------
__global__ __launch_bounds__(256) void prep_kernel(
    const int* __restrict__ g, const int* __restrict__ ingr,
    const float* __restrict__ wv, const float* __restrict__ Ug,
    const float* __restrict__ Ym, const float* __restrict__ yb,
    float* __restrict__ E_ws, float* __restrict__ sumE,
    float* __restrict__ goal_ws, float* HT2, float* TMP)
{
  __shared__ float ge[256];
  const int b = blockIdx.x, tid = threadIdx.x;
  float s = 0.f;
  for (int i = 0; i < 8; ++i) s += wv[((size_t)g[(b << 3) + i] << 8) + tid];
  ge[tid] = s;
  __syncthreads();
  float h0 = 0.f, gt = 0.f;
  const float* ur = Ug + (tid << 8);
  const float* yr = Ym + (tid << 8);
#pragma unroll 8
  for (int k = 0; k < Hd; k += 4) {
    float4 gv = *(const float4*)(ge + k);
    float4 uv = *(const float4*)(ur + k);
    float4 yv = *(const float4*)(yr + k);
    h0 = fmaf(gv.x, uv.x, h0); h0 = fmaf(gv.y, uv.y, h0);
    h0 = fmaf(gv.z, uv.z, h0); h0 = fmaf(gv.w, uv.w, h0);
    gt = fmaf(gv.x, yv.x, gt); gt = fmaf(gv.y, yv.y, gt);
    gt = fmaf(gv.z, yv.z, gt); gt = fmaf(gv.w, yv.w, gt);
  }
  st_dev(HT2 + (tid << 4) + b, h0);          // HT2 layout [c][b]
  goal_ws[(tid << 4) + b] = gt + yb[tid];    // goal_term layout [c][b]
  float se = 0.f;
  for (int l = 0; l < Ld; ++l) {
    float v = wv[((size_t)ingr[b * Ld + l] << 8) + tid];
    E_ws[((size_t)(b * Ld + l) << 8) + tid] = v;
    se += v;
  }
  sumE[(b << 8) + tid] = se;                 // [b][k]
  st_dev(TMP + (b << 8) + tid, se);          // tmp(0) = sumE
}

// ---------------- bf16 MFMA GEMM (128x128 tile, K=256), two epilogues ----------------
template <int MODE>
__global__ __launch_bounds__(256) void gemm_bf16(
    const unsigned short* __restrict__ A, const unsigned short* __restrict__ Bmat,
    const int* __restrict__ ridx, const float* __restrict__ bias,
    float* __restrict__ C)
{
  __shared__ unsigned short As[128 * 64];
  __shared__ unsigned short Bs[128 * 64];
  const int tid = threadIdx.x;
  const int m0 = blockIdx.x << 7, n0 = blockIdx.y << 7;
  const int wave = tid >> 6, lane = tid & 63;
  const int wm = wave >> 1, wn = wave & 1;
  const int lr = lane & 15, lg = lane >> 4;

  f32x4 acc[4][4];
#pragma unroll
  for (int i = 0; i < 4; ++i)
#pragma unroll
    for (int jj = 0; jj < 4; ++jj) acc[i][jj] = (f32x4){0.f, 0.f, 0.f, 0.f};

  const int srow = tid >> 1, shalf = tid & 1;
  const unsigned short* arow;
  {
    int gm = m0 + srow;
    if (MODE == 0) {
      int tt = gm >> 4, bb = gm & 15;
      arow = A + (size_t)ridx[bb * Td + tt] * Hd;
    } else {
      arow = A + (size_t)gm * Hd;
    }
  }
  const unsigned short* brow = Bmat + (size_t)(n0 + srow) * Hd;

  for (int k0 = 0; k0 < Hd; k0 += 64) {
#pragma unroll
    for (int c = 0; c < 4; ++c) {
      int k = shalf * 32 + c * 8;
      uint4 va = *(const uint4*)(arow + k0 + k);
      uint4 vb = *(const uint4*)(brow + k0 + k);
      int byo = (srow << 7) + ((k << 1) ^ ((srow & 7) << 4));  // XOR swizzle
      *(uint4*)((char*)As + byo) = va;
      *(uint4*)((char*)Bs + byo) = vb;
    }
    __syncthreads();
#pragma unroll
    for (int kk = 0; kk < 2; ++kk) {
      short8v af[4], bfr[4];
      const int kb = kk * 32 + lg * 8;
#pragma unroll
      for (int i = 0; i < 4; ++i) {
        int ar = wm * 64 + i * 16 + lr;
        af[i] = *(const short8v*)((const char*)As + (ar << 7) + ((kb << 1) ^ ((ar & 7) << 4)));
        int br = wn * 64 + i * 16 + lr;
        bfr[i] = *(const short8v*)((const char*)Bs + (br << 7) + ((kb << 1) ^ ((br & 7) << 4)));
      }
#pragma unroll
      for (int i = 0; i < 4; ++i)
#pragma unroll
        for (int jj = 0; jj < 4; ++jj)
          acc[i][jj] = __builtin_amdgcn_mfma_f32_16x16x32_bf16(af[i], bfr[jj], acc[i][jj], 0, 0, 0);
    }
    __syncthreads();
  }
#pragma unroll
  for (int i = 0; i < 4; ++i)
#pragma unroll
    for (int jj = 0; jj < 4; ++jj) {
      int col = n0 + wn * 64 + jj * 16 + lr;
      float bv = bias[col];
#pragma unroll
      for (int r = 0; r < 4; ++r) {
        int row = m0 + wm * 64 + i * 16 + lg * 4 + r;
        float v = acc[i][jj][r] + bv;
        if (MODE == 0) {
          int tt = row >> 4, bb = row & 15;
          C[((size_t)tt * G5H + col) * Bd + bb] = v;
        } else {
          C[(size_t)row * Vd + col] = v;
        }
      }
    }
}

// ---------------- persistent recurrence kernel v2 ----------------
// 16 WGs; 2 flag-barriers/step. WG j owns h-cols [16j,16j+16) (w_hh split-bf16
// slice in LDS, gh via MFMA) and batch j for attention.
#define RNN_SMEM 158208
__global__ __launch_bounds__(640, 1) void rnn_kernel(
    const float* __restrict__ w_hh, const float* __restrict__ b_hh,
    const float* __restrict__ Zm, const float* __restrict__ Pm,
    const float* __restrict__ Sm, const float* __restrict__ z_bias,
    const float* __restrict__ gi, const float* __restrict__ goal_ws,
    const float* __restrict__ E_ws, const float* __restrict__ sumE,
    float* HT2, float* TMP, float* HPART,
    unsigned short* __restrict__ out_all, float* __restrict__ d_out,
    unsigned* bar)
{
  extern __shared__ char smem[];
  float* tmp_lds  = (float*)smem;            // 16*260
  float* gh_lds   = tmp_lds + 16 * 260;      // 80*16
  float* zd_lds   = gh_lds + 1280;           // 256
  float* pv_lds   = zd_lds + 256;            // 2*256  ([cl][b] ping-pong)
  float* hrow_lds = pv_lds + 512;            // 256
  float* hp_lds   = hrow_lds + 256;          // 256
  float* se_lds   = hp_lds + 256;            // 256
  float* gl_lds   = se_lds + 256;            // 256 ([cl][b])
  float* bh_lds   = gl_lds + 256;            // 80
  float* zb_lds   = bh_lds + 80;             // 16
  float* a_lds    = zb_lds + 16;             // 64
  float* d_lds    = a_lds + 64;              // 64
  float* an_lds   = d_lds + 64;              // 64
  float* au_lds   = an_lds + 64;             // 64
  float* sd_lds   = au_lds + 64;             // 4
  float* ref_lds  = sd_lds + 4;              // 4
  unsigned short* w_hi  = (unsigned short*)(ref_lds + 4);  // 80*264
  unsigned short* w_lo  = w_hi + 80 * 264;
  unsigned short* ht_hi = w_lo + 80 * 264;                 // 16*264 ([b][c])
  unsigned short* ht_lo = ht_hi + 16 * 264;
  unsigned short* E_lds = ht_lo + 16 * 264;                // 50*264

  const int j = blockIdx.x;
  const int tid = threadIdx.x;
  const int lane = tid & 63, wid = tid >> 6;
  const int hc0 = j << 4;
  unsigned* flagsA = bar;
  unsigned* flagsB = bar + 16;

  // ---- one-time staging ----
  for (int idx = tid; idx < 80 * 256; idx += 640) {   // w_hh slice, split hi/lo
    int r = idx >> 8, k = idx & 255;
    int grow = ((r >> 4) << 8) + hc0 + (r & 15);
    float v = w_hh[((size_t)grow << 8) + k];
    unsigned short hi = f2bu(v);
    w_hi[r * 264 + k] = hi;
    w_lo[r * 264 + k] = f2bu(v - bu2f(hi));
  }
  for (int idx = tid; idx < Ld * 256; idx += 640) {   // E bf16
    int l = idx >> 8, k = idx & 255;
    E_lds[l * 264 + k] = f2bu(E_ws[((size_t)(j * Ld + l) << 8) + k]);
  }
  if (tid < 80) bh_lds[tid] = b_hh[((tid >> 4) << 8) + hc0 + (tid & 15)];
  if (tid < 16) zb_lds[tid] = z_bias[hc0 + tid];
  if (tid < 256) {
    se_lds[tid] = sumE[(j << 8) + tid];
    int cl = tid >> 4, b = tid & 15;
    gl_lds[tid] = goal_ws[((hc0 + cl) << 4) + b];
  }
  if (tid < 64) a_lds[tid] = 0.f;
  if (tid < 256) {                                     // initial ht0 stage
    int c = tid;
#pragma unroll
    for (int b = 0; b < 16; ++b) {
      float v = ld_dev(HT2 + (c << 4) + b);
      unsigned short hi = f2bu(v);
      ht_hi[b * 264 + c] = hi;
      ht_lo[b * 264 + c] = f2bu(v - bu2f(hi));
      if (c >= hc0 && c < hc0 + 16) pv_lds[(c - hc0) * 16 + b] = v;
    }
  }
  __syncthreads();

  for (int t = 0; t < Td; ++t) {
    float* pv_cur = pv_lds + ((t & 1) << 8);
    float* pv_nxt = pv_lds + (((t & 1) ^ 1) << 8);
    // ================= phase A =================
    for (int idx = tid; idx < 4096; idx += 640) {      // stage tmp(t)
      tmp_lds[(idx >> 8) * 260 + (idx & 255)] = ld_dev(TMP + idx);
    }
    __syncthreads();
    if (wid < 5) {                                     // gh slice via split MFMA
      const int g = wid, lr = lane & 15, lg = lane >> 4;
      const unsigned short* wh = w_hi + (g * 16 + lr) * 264;
      const unsigned short* wl = w_lo + (g * 16 + lr) * 264;
      const unsigned short* hh = ht_hi + lr * 264;
      const unsigned short* hl = ht_lo + lr * 264;
      f32x4 acc = (f32x4){0.f, 0.f, 0.f, 0.f};
#pragma unroll
      for (int k0 = 0; k0 < 256; k0 += 32) {
        int ko = k0 + lg * 8;
        short8v a_hi = *(const short8v*)(wh + ko);
        short8v a_lo = *(const short8v*)(wl + ko);
        short8v b_hi = *(const short8v*)(hh + ko);
        short8v b_lo = *(const short8v*)(hl + ko);
        acc = __builtin_amdgcn_mfma_f32_16x16x32_bf16(a_hi, b_hi, acc, 0, 0, 0);
        acc = __builtin_amdgcn_mfma_f32_16x16x32_bf16(a_hi, b_lo, acc, 0, 0, 0);
        acc = __builtin_amdgcn_mfma_f32_16x16x32_bf16(a_lo, b_hi, acc, 0, 0, 0);
      }
#pragma unroll
      for (int r = 0; r < 4; ++r)
        gh_lds[(g * 16 + lg * 4 + r) * 16 + lr] = acc[r];
    } else if (wid < 9) {                              // zd = Z_slice @ tmp
      int u = tid - 320;
      int cl = u >> 4, b = u & 15;
      const float* zr = Zm + ((size_t)(hc0 + cl) << 8);
      const float* tp = tmp_lds + b * 260;
      float s0 = 0.f, s1 = 0.f;
#pragma unroll 4
      for (int k = 0; k < 256; k += 8) {
        float4 z0 = *(const float4*)(zr + k);
        float4 z1 = *(const float4*)(zr + k + 4);
        float4 t0 = *(const float4*)(tp + k);
        float4 t1 = *(const float4*)(tp + k + 4);
        s0 = fmaf(z0.x, t0.x, s0); s0 = fmaf(z0.y, t0.y, s0);
        s0 = fmaf(z0.z, t0.z, s0); s0 = fmaf(z0.w, t0.w, s0);
        s1 = fmaf(z1.x, t1.x, s1); s1 = fmaf(z1.y, t1.y, s1);
        s1 = fmaf(z1.z, t1.z, s1); s1 = fmaf(z1.w, t1.w, s1);
      }
      zd_lds[cl * 16 + b] = s0 + s1;
    }
    __syncthreads();
    if (tid < 256) {                                   // gates -> ht2 slice
      int cl = tid >> 4, b = tid & 15;
      int c = hc0 + cl;
      float hr = gh_lds[(cl)*16 + b]        + bh_lds[cl];
      float hu = gh_lds[(16 + cl)*16 + b]   + bh_lds[16 + cl];
      float hn = gh_lds[(32 + cl)*16 + b]   + bh_lds[32 + cl];
      float hg = gh_lds[(48 + cl)*16 + b]   + bh_lds[48 + cl];
      float hq = gh_lds[(64 + cl)*16 + b]   + bh_lds[64 + cl];
      size_t gib = ((size_t)t * G5H) << 4;
      float i_r = gi[gib + (((size_t)(0 * 256 + c)) << 4) + b];
      float i_u = gi[gib + (((size_t)(256 + c)) << 4) + b];
      float i_n = gi[gib + (((size_t)(512 + c)) << 4) + b];
      float i_g = gi[gib + (((size_t)(768 + c)) << 4) + b];
      float i_i = gi[gib + (((size_t)(1024 + c)) << 4) + b];
      float rt = sigm(i_r + hr), zt = sigm(i_u + hu);
      float st = sigm(i_g + hg), qt = sigm(i_i + hq);
      float htl = tanhf(i_n + rt * hn + st * gl_lds[tid] + qt * (zd_lds[tid] + zb_lds[cl]));
      float prev = pv_cur[cl * 16 + b];
      float h2 = htl + zt * (prev - htl);
      st_dev(HT2 + (c << 4) + b, h2);
      pv_nxt[cl * 16 + b] = h2;
    }
    __syncthreads();
    if (tid < 512) {                                   // hpart: P col-slice @ ht2slice
      int c = tid >> 1, bh = tid & 1;
      const float* pr = Pm + ((size_t)c << 8) + hc0;
      float p[16];
#pragma unroll
      for (int q = 0; q < 4; ++q) {
        float4 v = *(const float4*)(pr + q * 4);
        p[q * 4] = v.x; p[q * 4 + 1] = v.y; p[q * 4 + 2] = v.z; p[q * 4 + 3] = v.w;
      }
      float acc[8];
#pragma unroll
      for (int i = 0; i < 8; ++i) acc[i] = 0.f;
#pragma unroll
      for (int kl = 0; kl < 16; ++kl) {
        float pp = p[kl];
        float4 s0 = *(const float4*)(pv_nxt + kl * 16 + bh * 8);
        float4 s1 = *(const float4*)(pv_nxt + kl * 16 + bh * 8 + 4);
        acc[0] = fmaf(pp, s0.x, acc[0]); acc[1] = fmaf(pp, s0.y, acc[1]);
        acc[2] = fmaf(pp, s0.z, acc[2]); acc[3] = fmaf(pp, s0.w, acc[3]);
        acc[4] = fmaf(pp, s1.x, acc[4]); acc[5] = fmaf(pp, s1.y, acc[5]);
        acc[6] = fmaf(pp, s1.z, acc[6]); acc[7] = fmaf(pp, s1.w, acc[7]);
      }
#pragma unroll
      for (int i = 0; i < 8; ++i)
        st_dev(HPART + (c << 8) + ((bh * 8 + i) << 4) + j, acc[i]);
    }
    // ---- barrier A ----
    asm volatile("s_waitcnt vmcnt(0)" ::: "memory");
    __syncthreads();
    if (tid < 64) {
      unsigned tgt = (unsigned)(t + 1);
      if (lane == 0)
        __hip_atomic_store(flagsA + j, tgt, __ATOMIC_RELEASE, __HIP_MEMORY_SCOPE_AGENT);
      int guard = 0;
      while (1) {
        unsigned v = (lane < 16)
          ? __hip_atomic_load(flagsA + lane, __ATOMIC_RELAXED, __HIP_MEMORY_SCOPE_AGENT)
          : tgt;
        if (__all((int)(v >= tgt))) break;
        if (++guard > (1 << 20)) break;
      }
    }
    __syncthreads();
    // ================= phase B =================
    if (tid < 256) {                                   // stage ht2(t) full
      int c = tid;
#pragma unroll
      for (int b = 0; b < 16; ++b) {
        float v = ld_dev(HT2 + (c << 4) + b);
        unsigned short hi = f2bu(v);
        ht_hi[b * 264 + c] = hi;
        ht_lo[b * 264 + c] = f2bu(v - bu2f(hi));
        if (b == j) hrow_lds[c] = v;
      }
    } else if (tid < 512) {                            // hproj[j] = sum of partials
      int c = tid - 256;
      const float* hp = HPART + (c << 8) + (j << 4);
      float s = 0.f;
#pragma unroll
      for (int jj = 0; jj < 16; ++jj) s += ld_dev(hp + jj);
      hp_lds[c] = s;
    }
    __syncthreads();
    if (tid < 192) {                                   // S dots
      int w = tid >> 6, ln = tid & 63;
      float4 sv = *(const float4*)(Sm + (w << 8) + (ln << 2));
      float4 hv = *(const float4*)(hrow_lds + (ln << 2));
      float p = sv.x * hv.x + sv.y * hv.y + sv.z * hv.z + sv.w * hv.w;
      p += __shfl_xor(p, 1);  p += __shfl_xor(p, 2);  p += __shfl_xor(p, 4);
      p += __shfl_xor(p, 8);  p += __shfl_xor(p, 16); p += __shfl_xor(p, 32);
      if (ln == 0) sd_lds[w] = p;
    } else if (tid >= 256 && tid < 456) {              // d_l = h_proj . E_l
      int u = tid - 256;
      int l = u >> 2, q = u & 3;
      const unsigned short* er = E_lds + l * 264 + (q << 6);
      const float* hq = hp_lds + (q << 6);
      float p = 0.f;
#pragma unroll 8
      for (int i = 0; i < 32; ++i) {
        unsigned uu = *(const unsigned*)(er + 2 * i);
        float e0 = __uint_as_float(uu << 16);
        float e1 = __uint_as_float(uu & 0xffff0000u);
        p = fmaf(e0, hq[2 * i], p);
        p = fmaf(e1, hq[2 * i + 1], p);
      }
      p += __shfl_xor(p, 1); p += __shfl_xor(p, 2);
      if (q == 0) d_lds[l] = p;
    }
    __syncthreads();
    if (tid < 128) {                                   // alpha_n / alpha_u
      int which = tid >> 6;
      int l = tid & 63;
      float dv;
      if (which == 0) dv = (l < Ld) ? 2.0f * (1.f - a_lds[l]) * d_lds[l] : -3.4e38f;
      else            dv = (l < Ld) ? 2.0f * a_lds[l] * d_lds[l]         : -3.4e38f;
      float m = dv;
      m = fmaxf(m, __shfl_xor(m, 1));  m = fmaxf(m, __shfl_xor(m, 2));
      m = fmaxf(m, __shfl_xor(m, 4));  m = fmaxf(m, __shfl_xor(m, 8));
      m = fmaxf(m, __shfl_xor(m, 16)); m = fmaxf(m, __shfl_xor(m, 32));
      float e = (l < Ld) ? __expf(dv - m) : 0.f;
      float ss = e;
      ss += __shfl_xor(ss, 1);  ss += __shfl_xor(ss, 2);  ss += __shfl_xor(ss, 4);
      ss += __shfl_xor(ss, 8);  ss += __shfl_xor(ss, 16); ss += __shfl_xor(ss, 32);
      float al = e / ss;
      if (which == 0) an_lds[l] = al; else au_lds[l] = al;
    } else if (tid == 192) {                           // ref = softmax(BETA*sd)
      float s0 = 5.0f * sd_lds[0], s1 = 5.0f * sd_lds[1], s2 = 5.0f * sd_lds[2];
      float m = fmaxf(s0, fmaxf(s1, s2));
      float e0 = __expf(s0 - m), e1 = __expf(s1 - m), e2 = __expf(s2 - m);
      float inv = 1.f / (e0 + e1 + e2);
      ref_lds[0] = e0 * inv; ref_lds[1] = e1 * inv; ref_lds[2] = e2 * inv;
    }
    __syncthreads();
    if (tid < 256) {                                   // c_n, c_u, out, tmp(t+1)
      int k = tid;
      float accn = 0.f, accu = 0.f, acct = 0.f;
#pragma unroll 10
      for (int l = 0; l < Ld; ++l) {
        float e = bu2f(E_lds[l * 264 + k]);
        accn = fmaf(an_lds[l], e, accn);
        accu = fmaf(au_lds[l], e, accu);
        acct = fmaf(a_lds[l], e, acct);
      }
      float outv = ref_lds[0] * hp_lds[k] + ref_lds[1] * accn + ref_lds[2] * accu;
      out_all[(((j << 7) + t) << 8) + k] = f2bu(outv);
      st_dev(TMP + (j << 8) + k, se_lds[k] - acct);
      if (t == Td - 1) {
        d_out[(size_t)65536000 + (j << 8) + k] = hrow_lds[k];
        for (int l = 0; l < Ld; ++l) {
          size_t o = ((size_t)(j * Ld + l) << 8) + k;
          d_out[(size_t)65540896 + o] = (1.f - a_lds[l]) * E_ws[o];
        }
      }
    }
    __syncthreads();
    if (tid < Ld) {                                    // a update
      float na = a_lds[tid] + ref_lds[1] * an_lds[tid];
      a_lds[tid] = na;
      if (t == Td - 1) d_out[(size_t)65540096 + j * Ld + tid] = na;
    }
    // ---- barrier B ----
    asm volatile("s_waitcnt vmcnt(0)" ::: "memory");
    __syncthreads();
    if (tid < 64) {
      unsigned tgt = (unsigned)(t + 1);
      if (lane == 0)
        __hip_atomic_store(flagsB + j, tgt, __ATOMIC_RELEASE, __HIP_MEMORY_SCOPE_AGENT);
      int guard = 0;
      while (1) {
        unsigned v = (lane < 16)
          ? __hip_atomic_load(flagsB + lane, __ATOMIC_RELAXED, __HIP_MEMORY_SCOPE_AGENT)
          : tgt;
        if (__all((int)(v >= tgt))) break;
        if (++guard > (1 << 20)) break;
      }
    }
    __syncthreads();
  }
}

// ---------------- host launcher ----------------
extern "C" void kernel_launch(void* const* d_in, const int* in_sizes, int n_in,
                              void* d_out, int out_size, void* d_ws, size_t ws_size,
                              hipStream_t stream)
{
  const int*   recipe = (const int*)d_in[0];
  const int*   g      = (const int*)d_in[1];
  const int*   ingr   = (const int*)d_in[2];
  const float* wv     = (const float*)d_in[3];
  const float* w_ih   = (const float*)d_in[4];
  const float* w_hh   = (const float*)d_in[5];
  const float* b_ih   = (const float*)d_in[6];
  const float* b_hh   = (const float*)d_in[7];
  const float* Z      = (const float*)d_in[8];
  const float* Y      = (const float*)d_in[9];
  const float* Ug     = (const float*)d_in[10];
  const float* z_bias = (const float*)d_in[11];
  const float* y_bias = (const float*)d_in[12];
  const float* S      = (const float*)d_in[13];
  const float* P      = (const float*)d_in[14];
  const float* fcW    = (const float*)d_in[15];
  const float* fcb    = (const float*)d_in[16];
  float* out = (float*)d_out;
  char* ws = (char*)d_ws;

  size_t off = 0;
  unsigned* bar            = (unsigned*)(ws + off);        off += 256;
  unsigned short* wv_b     = (unsigned short*)(ws + off);  off += 16384000;
  unsigned short* wih_b    = (unsigned short*)(ws + off);  off += 655360;
  unsigned short* fcw_b    = (unsigned short*)(ws + off);  off += 16384000;
  float* gi_ws             = (float*)(ws + off);           off += 10485760;
  float* E_ws              = (float*)(ws + off);           off += 819200;
  float* sumE              = (float*)(ws + off);           off += 16384;
  float* goal_ws           = (float*)(ws + off);           off += 16384;
  float* HT2               = (float*)(ws + off);           off += 16384;
  float* TMP               = (float*)(ws + off);           off += 16384;
  float* HPART             = (float*)(ws + off);           off += 262144;
  unsigned short* out_all  = (unsigned short*)(ws + off);  off += 1048576;

  hipMemsetAsync(bar, 0, 256, stream);
  conv_kernel<<<2048, 256, 0, stream>>>(wv, w_ih, fcW, wv_b, wih_b, fcw_b);
  prep_kernel<<<16, 256, 0, stream>>>(g, ingr, wv, Ug, Y, y_bias,
                                      E_ws, sumE, goal_ws, HT2, TMP);
  gemm_bf16<0><<<dim3(16, 10), 256, 0, stream>>>(wv_b, wih_b, recipe, b_ih, gi_ws);
  hipFuncSetAttribute((const void*)rnn_kernel,
                      hipFuncAttributeMaxDynamicSharedMemorySize, RNN_SMEM);
  rnn_kernel<<<16, 640, RNN_SMEM, stream>>>(w_hh, b_hh, Z, P, S, z_bias,
                                            gi_ws, goal_ws, E_ws, sumE,
                                            HT2, TMP, HPART, out_all, out, bar);
  gemm_bf16<1><<<dim3(16, 250), 256, 0, stream>>>(out_all, fcw_b, nullptr, fcb, out);
}